// Round 1
// baseline (5855.979 us; speedup 1.0000x reference)
//
#include <hip/hip_runtime.h>

#define N_NODES 100000
#define N_EDGES 100000
#define NNZ_CNT 1600000
#define DIN 128
#define DOUT 128

// h = x @ W  (one block per node row, 128 threads = one output col each)
__global__ void gemm_xw_kernel(const float* __restrict__ x,
                               const float* __restrict__ w,
                               float* __restrict__ h) {
    const int row = blockIdx.x;
    const int j = threadIdx.x;
    __shared__ float xs[DIN];
    xs[j] = x[(long long)row * DIN + j];
    __syncthreads();
    float acc = 0.f;
#pragma unroll 16
    for (int k = 0; k < DIN; ++k) {
        acc += xs[k] * w[k * DOUT + j];
    }
    h[(long long)row * DOUT + j] = acc;
}

// node degree D and hyperedge degree B via scalar atomics
__global__ void degree_kernel(const int* __restrict__ nidx,
                              const int* __restrict__ eidx,
                              float* __restrict__ D,
                              float* __restrict__ B) {
    const int i = blockIdx.x * blockDim.x + threadIdx.x;
    if (i < NNZ_CNT) {
        atomicAdd(&D[nidx[i]], 1.0f);
        atomicAdd(&B[eidx[i]], 1.0f);
    }
}

// e_acc[edge] += h[node]   (32 threads per incidence entry, float4 each)
__global__ void scatter_n2e_kernel(const int* __restrict__ nidx,
                                   const int* __restrict__ eidx,
                                   const float* __restrict__ h,
                                   float* __restrict__ e_acc) {
    const long long t = (long long)blockIdx.x * blockDim.x + threadIdx.x;
    const long long nz = t >> 5;   // 32 threads per nnz
    const int lane = (int)(t & 31);
    if (nz >= NNZ_CNT) return;
    const int n = nidx[nz];
    const int e = eidx[nz];
    const float4 v = ((const float4*)(h + (long long)n * DOUT))[lane];
    float* dst = e_acc + (long long)e * DOUT + lane * 4;
    atomicAdd(dst + 0, v.x);
    atomicAdd(dst + 1, v.y);
    atomicAdd(dst + 2, v.z);
    atomicAdd(dst + 3, v.w);
}

// out[node] += e_acc[edge] * (1/B[edge])
__global__ void scatter_e2n_kernel(const int* __restrict__ nidx,
                                   const int* __restrict__ eidx,
                                   const float* __restrict__ e_acc,
                                   const float* __restrict__ B,
                                   float* __restrict__ out) {
    const long long t = (long long)blockIdx.x * blockDim.x + threadIdx.x;
    const long long nz = t >> 5;
    const int lane = (int)(t & 31);
    if (nz >= NNZ_CNT) return;
    const int n = nidx[nz];
    const int e = eidx[nz];
    const float binv = 1.0f / B[e];   // e appears in the list => B[e] >= 1
    const float4 v = ((const float4*)(e_acc + (long long)e * DOUT))[lane];
    float* dst = out + (long long)n * DOUT + lane * 4;
    atomicAdd(dst + 0, v.x * binv);
    atomicAdd(dst + 1, v.y * binv);
    atomicAdd(dst + 2, v.z * binv);
    atomicAdd(dst + 3, v.w * binv);
}

// out = out * Dinv + bias
__global__ void finalize_kernel(float* __restrict__ out,
                                const float* __restrict__ D,
                                const float* __restrict__ bias) {
    const int i = blockIdx.x * blockDim.x + threadIdx.x;
    if (i < N_NODES * DOUT) {
        const int row = i >> 7;
        const int col = i & 127;
        const float d = D[row];
        const float dinv = d > 0.f ? 1.0f / d : 0.f;
        out[i] = out[i] * dinv + bias[col];
    }
}

extern "C" void kernel_launch(void* const* d_in, const int* in_sizes, int n_in,
                              void* d_out, int out_size, void* d_ws, size_t ws_size,
                              hipStream_t stream) {
    const float* x = (const float*)d_in[0];
    const float* w = (const float*)d_in[1];
    const float* bias = (const float*)d_in[2];
    const int* hei = (const int*)d_in[3];      // [2, NNZ] row-major, int32
    const int* nidx = hei;                     // row 0: node indices
    const int* eidx = hei + NNZ_CNT;           // row 1: edge indices
    float* out = (float*)d_out;

    // workspace layout (floats): h [N*128] | e_acc [E*128] | D [N] | B [E]
    float* h = (float*)d_ws;
    float* e_acc = h + (long long)N_NODES * DOUT;
    float* D = e_acc + (long long)N_EDGES * DOUT;
    float* B = D + N_NODES;

    // zero the accumulators (ws and out are poisoned to 0xAA before each run)
    hipMemsetAsync(e_acc, 0, (size_t)N_EDGES * DOUT * sizeof(float), stream);
    hipMemsetAsync(D, 0, (size_t)N_NODES * sizeof(float), stream);
    hipMemsetAsync(B, 0, (size_t)N_EDGES * sizeof(float), stream);
    hipMemsetAsync(out, 0, (size_t)N_NODES * DOUT * sizeof(float), stream);

    // 1) h = x @ W
    gemm_xw_kernel<<<N_NODES, DIN, 0, stream>>>(x, w, h);

    // 2) degrees
    degree_kernel<<<(NNZ_CNT + 255) / 256, 256, 0, stream>>>(nidx, eidx, D, B);

    // 3) nodes -> edges
    {
        const long long total = (long long)NNZ_CNT * 32;
        scatter_n2e_kernel<<<(int)((total + 255) / 256), 256, 0, stream>>>(nidx, eidx, h, e_acc);
    }

    // 4) edges -> nodes (fold in 1/B)
    {
        const long long total = (long long)NNZ_CNT * 32;
        scatter_e2n_kernel<<<(int)((total + 255) / 256), 256, 0, stream>>>(nidx, eidx, e_acc, B, out);
    }

    // 5) out = out * Dinv + bias
    finalize_kernel<<<(N_NODES * DOUT + 255) / 256, 256, 0, stream>>>(out, D, bias);
}

// Round 2
// 778.539 us; speedup vs baseline: 7.5218x; 7.5218x over previous
//
#include <hip/hip_runtime.h>

#define Nn 100000
#define Ne 100000
#define NNZC 1600000
#define NB 391  // ceil(100000/256)

__device__ inline float bf2f(unsigned short u) {
    union { unsigned int i; float f; } c; c.i = ((unsigned int)u) << 16; return c.f;
}
__device__ inline unsigned short f2bf(float f) {
    union { float f; unsigned int i; } c; c.f = f;
    unsigned int i = c.i;
    return (unsigned short)((i + 0x7fffu + ((i >> 16) & 1u)) >> 16);  // RNE
}

// ---- degree count (int atomics, cheap) ----
__global__ void degree_kernel(const int* __restrict__ nidx, const int* __restrict__ eidx,
                              int* __restrict__ cntN, int* __restrict__ cntE) {
    int i = blockIdx.x * blockDim.x + threadIdx.x;
    if (i < NNZC) {
        atomicAdd(&cntN[nidx[i]], 1);
        atomicAdd(&cntE[eidx[i]], 1);
    }
}

// ---- 3-phase exclusive scan over both 100k count arrays ----
__global__ void scan1_kernel(const int* __restrict__ cntN, const int* __restrict__ cntE,
                             int* __restrict__ offsN, int* __restrict__ offsE,
                             int* __restrict__ bsumN, int* __restrict__ bsumE) {
    const int arr = blockIdx.x / NB;
    const int b = blockIdx.x % NB;
    const int* cnt = arr ? cntE : cntN;
    int* offs = arr ? offsE : offsN;
    int* bsum = arr ? bsumE : bsumN;
    const int t = threadIdx.x;
    const int idx = b * 256 + t;
    int v = (idx < 100000) ? cnt[idx] : 0;
    __shared__ int tmp[2][256];
    int pin = 0;
    tmp[0][t] = v;
    for (int off = 1; off < 256; off <<= 1) {
        __syncthreads();
        int val = tmp[pin][t];
        if (t >= off) val += tmp[pin][t - off];
        tmp[1 - pin][t] = val;
        pin ^= 1;
    }
    __syncthreads();
    int incl = tmp[pin][t];
    if (idx < 100000) offs[idx] = incl - v;   // exclusive
    if (t == 255) bsum[b] = incl;             // block total
}

__global__ void scan2_kernel(int* __restrict__ bsumN, int* __restrict__ bsumE) {
    int* bsum = blockIdx.x ? bsumE : bsumN;
    const int t = threadIdx.x;  // block 512
    int v = (t < NB) ? bsum[t] : 0;
    __shared__ int tmp[2][512];
    int pin = 0;
    tmp[0][t] = v;
    for (int off = 1; off < 512; off <<= 1) {
        __syncthreads();
        int val = tmp[pin][t];
        if (t >= off) val += tmp[pin][t - off];
        tmp[1 - pin][t] = val;
        pin ^= 1;
    }
    __syncthreads();
    if (t < NB) bsum[t] = tmp[pin][t] - v;    // exclusive block offsets
}

__global__ void scan3_kernel(int* __restrict__ offsN, int* __restrict__ offsE,
                             const int* __restrict__ bsumN, const int* __restrict__ bsumE) {
    const int arr = blockIdx.x / NB;
    const int b = blockIdx.x % NB;
    int* offs = arr ? offsE : offsN;
    const int* bsum = arr ? bsumE : bsumN;
    const int idx = b * 256 + threadIdx.x;
    if (idx < 100000) offs[idx] += bsum[b];
    if (b == 0 && threadIdx.x == 0) offs[100000] = NNZC;
}

// ---- fill CSR perm arrays (cursors = re-zeroed cnt arrays) ----
__global__ void fill_kernel(const int* __restrict__ nidx, const int* __restrict__ eidx,
                            const int* __restrict__ offsN, const int* __restrict__ offsE,
                            int* __restrict__ curN, int* __restrict__ curE,
                            int* __restrict__ permN, int* __restrict__ permE) {
    int i = blockIdx.x * blockDim.x + threadIdx.x;
    if (i < NNZC) {
        const int n = nidx[i];
        const int e = eidx[i];
        permE[offsE[e] + atomicAdd(&curE[e], 1)] = n;  // edge-grouped node list
        permN[offsN[n] + atomicAdd(&curN[n], 1)] = e;  // node-grouped edge list
    }
}

// ---- h = x @ W, bf16 output. 8 rows/block, 128 threads (col each). ----
#define GROWS 8
__global__ void gemm_kernel(const float* __restrict__ x, const float* __restrict__ w,
                            unsigned short* __restrict__ h) {
    const int j = threadIdx.x;
    const int row0 = blockIdx.x * GROWS;
    const float* xr = x + (size_t)row0 * 128;  // wave-uniform reads -> s_load
    float acc[GROWS];
#pragma unroll
    for (int r = 0; r < GROWS; ++r) acc[r] = 0.f;
#pragma unroll 4
    for (int k = 0; k < 128; ++k) {
        const float wk = w[k * 128 + j];
#pragma unroll
        for (int r = 0; r < GROWS; ++r) acc[r] += xr[r * 128 + k] * wk;
    }
#pragma unroll
    for (int r = 0; r < GROWS; ++r) h[(size_t)(row0 + r) * 128 + j] = f2bf(acc[r]);
}

// ---- nodes -> edges: e_feat[e] = Binv * sum h[n], one wave per edge ----
__global__ void gather_n2e_kernel(const int* __restrict__ perm, const int* __restrict__ offs,
                                  const unsigned short* __restrict__ h,
                                  unsigned short* __restrict__ ef) {
    const int wave = threadIdx.x >> 6;
    const int lane = threadIdx.x & 63;
    const int e = blockIdx.x * 4 + wave;
    const int start = offs[e], end = offs[e + 1];
    float ax = 0.f, ay = 0.f;
    const ushort2* h2 = (const ushort2*)h;
    for (int s0 = start; s0 < end; s0 += 64) {
        const int m = end - s0;
        int myv = (lane < m) ? perm[s0 + lane] : 0;  // coalesced chunk read
        const int c = m < 64 ? m : 64;
        for (int t = 0; t < c; ++t) {
            const int n = __shfl(myv, t, 64);
            ushort2 v = h2[(size_t)n * 64 + lane];
            ax += bf2f(v.x);
            ay += bf2f(v.y);
        }
    }
    const int deg = end - start;
    const float binv = deg ? 1.f / (float)deg : 0.f;
    ushort2 o;
    o.x = f2bf(ax * binv);
    o.y = f2bf(ay * binv);
    ((ushort2*)ef)[(size_t)e * 64 + lane] = o;
}

// ---- edges -> nodes: out[n] = Dinv * sum e_feat[e] + bias ----
__global__ void gather_e2n_kernel(const int* __restrict__ perm, const int* __restrict__ offs,
                                  const unsigned short* __restrict__ ef,
                                  const float* __restrict__ bias,
                                  float* __restrict__ out) {
    const int wave = threadIdx.x >> 6;
    const int lane = threadIdx.x & 63;
    const int n = blockIdx.x * 4 + wave;
    const int start = offs[n], end = offs[n + 1];
    float ax = 0.f, ay = 0.f;
    const ushort2* e2 = (const ushort2*)ef;
    for (int s0 = start; s0 < end; s0 += 64) {
        const int m = end - s0;
        int myv = (lane < m) ? perm[s0 + lane] : 0;
        const int c = m < 64 ? m : 64;
        for (int t = 0; t < c; ++t) {
            const int e = __shfl(myv, t, 64);
            ushort2 v = e2[(size_t)e * 64 + lane];
            ax += bf2f(v.x);
            ay += bf2f(v.y);
        }
    }
    const int deg = end - start;
    const float dinv = deg ? 1.f / (float)deg : 0.f;
    const float2 b = ((const float2*)bias)[lane];
    float2 o;
    o.x = ax * dinv + b.x;
    o.y = ay * dinv + b.y;
    ((float2*)out)[(size_t)n * 64 + lane] = o;
}

extern "C" void kernel_launch(void* const* d_in, const int* in_sizes, int n_in,
                              void* d_out, int out_size, void* d_ws, size_t ws_size,
                              hipStream_t stream) {
    const float* x = (const float*)d_in[0];
    const float* w = (const float*)d_in[1];
    const float* bias = (const float*)d_in[2];
    const int* hei = (const int*)d_in[3];
    const int* nidx = hei;            // row 0: node indices
    const int* eidx = hei + NNZC;     // row 1: edge indices
    float* out = (float*)d_out;

    // ---- carve workspace (all chunks 256B-aligned) ----
    char* p = (char*)d_ws;
    unsigned short* h = (unsigned short*)p;      p += (size_t)Nn * 128 * 2;   // 25.6 MB
    unsigned short* ef = (unsigned short*)p;     p += (size_t)Ne * 128 * 2;   // 25.6 MB
    int* cntN = (int*)p;                         p += 400128;
    int* cntE = (int*)p;                         p += 400128;
    int* offsN = (int*)p;                        p += 400128;                 // 100001 ints
    int* offsE = (int*)p;                        p += 400128;
    int* bsumN = (int*)p;                        p += 1792;
    int* bsumE = (int*)p;                        p += 1792;
    int* permE = (int*)p;                        p += (size_t)NNZC * 4;       // 6.4 MB
    int* permN = (int*)p;                        p += (size_t)NNZC * 4;       // 6.4 MB

    // ---- CSR build ----
    hipMemsetAsync(cntN, 0, 100000 * sizeof(int), stream);
    hipMemsetAsync(cntE, 0, 100000 * sizeof(int), stream);
    degree_kernel<<<(NNZC + 255) / 256, 256, 0, stream>>>(nidx, eidx, cntN, cntE);
    scan1_kernel<<<2 * NB, 256, 0, stream>>>(cntN, cntE, offsN, offsE, bsumN, bsumE);
    hipMemsetAsync(cntN, 0, 100000 * sizeof(int), stream);  // reuse as cursors
    hipMemsetAsync(cntE, 0, 100000 * sizeof(int), stream);
    scan2_kernel<<<2, 512, 0, stream>>>(bsumN, bsumE);
    scan3_kernel<<<2 * NB, 256, 0, stream>>>(offsN, offsE, bsumN, bsumE);
    fill_kernel<<<(NNZC + 255) / 256, 256, 0, stream>>>(nidx, eidx, offsN, offsE,
                                                        cntN, cntE, permN, permE);

    // ---- dense transform ----
    gemm_kernel<<<Nn / GROWS, 128, 0, stream>>>(x, w, h);

    // ---- two gather-side segment sums ----
    gather_n2e_kernel<<<Ne / 4, 256, 0, stream>>>(permE, offsE, h, ef);
    gather_e2n_kernel<<<Nn / 4, 256, 0, stream>>>(permN, offsN, ef, bias, out);
}

// Round 3
// 435.184 us; speedup vs baseline: 13.4563x; 1.7890x over previous
//
#include <hip/hip_runtime.h>

#define Nn 100000
#define Ne 100000
#define NNZC 1600000
#define NBLK 256          // blocks for hist/scatter
#define CHUNK 6250        // NNZC / NBLK
#define BSH 7             // bucket = idx >> 7 (128 ids per bucket)
#define BUCKW 128
#define NBK 782           // ceil(100000/128)
#define SCANSZ (NBK * NBLK)  // 200192

__device__ inline float bf2f(unsigned short u) {
    union { unsigned int i; float f; } c; c.i = ((unsigned int)u) << 16; return c.f;
}
__device__ inline unsigned short f2bf(float f) {
    union { float f; unsigned int i; } c; c.f = f;
    unsigned int i = c.i;
    return (unsigned short)((i + 0x7fffu + ((i >> 16) & 1u)) >> 16);  // RNE
}

// ---- per-block bucket histograms for both directions ----
__global__ void hist_kernel(const int* __restrict__ nidx, const int* __restrict__ eidx,
                            int* __restrict__ histN, int* __restrict__ histE) {
    __shared__ int hN[NBK], hE[NBK];
    for (int j = threadIdx.x; j < NBK; j += 256) { hN[j] = 0; hE[j] = 0; }
    __syncthreads();
    const int base = blockIdx.x * CHUNK;
    for (int i = base + threadIdx.x; i < base + CHUNK; i += 256) {
        atomicAdd(&hN[nidx[i] >> BSH], 1);
        atomicAdd(&hE[eidx[i] >> BSH], 1);
    }
    __syncthreads();
    for (int j = threadIdx.x; j < NBK; j += 256) {
        histN[j * NBLK + blockIdx.x] = hN[j];   // bucket-major layout
        histE[j * NBLK + blockIdx.x] = hE[j];
    }
}

// ---- 3-phase exclusive scan over the two SCANSZ hist arrays (in place) ----
__global__ void scan1_kernel(int* __restrict__ histN, int* __restrict__ histE,
                             int* __restrict__ bsumN, int* __restrict__ bsumE) {
    const int arr = blockIdx.x / NBK;
    const int b = blockIdx.x % NBK;
    int* a = arr ? histE : histN;
    int* bs = arr ? bsumE : bsumN;
    const int t = threadIdx.x;
    int v = a[b * 256 + t];
    __shared__ int tmp[2][256];
    int pin = 0;
    tmp[0][t] = v;
    for (int off = 1; off < 256; off <<= 1) {
        __syncthreads();
        int val = tmp[pin][t];
        if (t >= off) val += tmp[pin][t - off];
        tmp[1 - pin][t] = val;
        pin ^= 1;
    }
    __syncthreads();
    int incl = tmp[pin][t];
    a[b * 256 + t] = incl - v;      // exclusive within block
    if (t == 255) bs[b] = incl;
}

__global__ void scan2_kernel(int* __restrict__ bsumN, int* __restrict__ bsumE) {
    int* bs = blockIdx.x ? bsumE : bsumN;
    const int t = threadIdx.x;  // 1024 threads
    int v = (t < NBK) ? bs[t] : 0;
    __shared__ int tmp[2][1024];
    int pin = 0;
    tmp[0][t] = v;
    for (int off = 1; off < 1024; off <<= 1) {
        __syncthreads();
        int val = tmp[pin][t];
        if (t >= off) val += tmp[pin][t - off];
        tmp[1 - pin][t] = val;
        pin ^= 1;
    }
    __syncthreads();
    if (t < NBK) bs[t] = tmp[pin][t] - v;   // exclusive block offsets
}

__global__ void scan3_kernel(int* __restrict__ histN, int* __restrict__ histE,
                             const int* __restrict__ bsumN, const int* __restrict__ bsumE) {
    const int arr = blockIdx.x / NBK;
    const int b = blockIdx.x % NBK;
    int* a = arr ? histE : histN;
    const int* bs = arr ? bsumE : bsumN;
    a[b * 256 + threadIdx.x] += bs[b];
}

// ---- scatter pairs into bucket-sorted order (block-exclusive runs) ----
__global__ void scatter_kernel(const int* __restrict__ nidx, const int* __restrict__ eidx,
                               const int* __restrict__ histN, const int* __restrict__ histE,
                               int2* __restrict__ pairsN, int2* __restrict__ pairsE) {
    __shared__ int cN[NBK], cE[NBK];
    const int blk = blockIdx.x;
    for (int j = threadIdx.x; j < NBK; j += 256) {
        cN[j] = histN[j * NBLK + blk];
        cE[j] = histE[j * NBLK + blk];
    }
    __syncthreads();
    const int base = blk * CHUNK;
    for (int i = base + threadIdx.x; i < base + CHUNK; i += 256) {
        const int n = nidx[i], e = eidx[i];
        const int pn = atomicAdd(&cN[n >> BSH], 1);
        const int pe = atomicAdd(&cE[e >> BSH], 1);
        pairsN[pn] = make_int2(n, e);   // grouped by node-bucket
        pairsE[pe] = make_int2(e, n);   // grouped by edge-bucket
    }
}

// ---- fine pass: per-bucket local counts -> per-id offsets + perm fill ----
__global__ void fine_kernel(const int2* __restrict__ pairsN, const int2* __restrict__ pairsE,
                            const int* __restrict__ histN, const int* __restrict__ histE,
                            int* __restrict__ offsN, int* __restrict__ offsE,
                            int* __restrict__ permN, int* __restrict__ permE) {
    const int arr = blockIdx.x / NBK;
    const int b = blockIdx.x % NBK;
    const int2* pairs = arr ? pairsE : pairsN;
    const int* hist = arr ? histE : histN;
    int* offs = arr ? offsE : offsN;
    int* perm = arr ? permE : permN;
    const int t = threadIdx.x;  // 128
    const int S = hist[b * NBLK];
    const int E = (b + 1 < NBK) ? hist[(b + 1) * NBLK] : NNZC;
    __shared__ int cnt[BUCKW];
    __shared__ int tmp[2][BUCKW];
    cnt[t] = 0;
    __syncthreads();
    for (int i = S + t; i < E; i += BUCKW)
        atomicAdd(&cnt[pairs[i].x & (BUCKW - 1)], 1);
    __syncthreads();
    // exclusive scan of 128 counts
    int v = cnt[t];
    int pin = 0;
    tmp[0][t] = v;
    for (int off = 1; off < BUCKW; off <<= 1) {
        __syncthreads();
        int val = tmp[pin][t];
        if (t >= off) val += tmp[pin][t - off];
        tmp[1 - pin][t] = val;
        pin ^= 1;
    }
    __syncthreads();
    const int excl = tmp[pin][t] - v;
    const int id = b * BUCKW + t;
    if (id < 100000) offs[id] = S + excl;
    if (b == NBK - 1 && t == 0) offs[100000] = NNZC;
    __syncthreads();
    cnt[t] = excl;   // reuse as cursors
    __syncthreads();
    for (int i = S + t; i < E; i += BUCKW) {
        const int2 p = pairs[i];
        const int pos = S + atomicAdd(&cnt[p.x & (BUCKW - 1)], 1);
        perm[pos] = p.y;
    }
}

// ---- h = x @ W, bf16 output ----
#define GROWS 8
__global__ void gemm_kernel(const float* __restrict__ x, const float* __restrict__ w,
                            unsigned short* __restrict__ h) {
    const int j = threadIdx.x;
    const int row0 = blockIdx.x * GROWS;
    const float* xr = x + (size_t)row0 * 128;
    float acc[GROWS];
#pragma unroll
    for (int r = 0; r < GROWS; ++r) acc[r] = 0.f;
#pragma unroll 4
    for (int k = 0; k < 128; ++k) {
        const float wk = w[k * 128 + j];
#pragma unroll
        for (int r = 0; r < GROWS; ++r) acc[r] += xr[r * 128 + k] * wk;
    }
#pragma unroll
    for (int r = 0; r < GROWS; ++r) h[(size_t)(row0 + r) * 128 + j] = f2bf(acc[r]);
}

// ---- gather with 4-way MLP unroll ----
__device__ inline void gather_rows(const ushort2* __restrict__ src, const int* __restrict__ perm,
                                   int start, int end, int lane, float& ax, float& ay) {
    for (int s0 = start; s0 < end; s0 += 64) {
        const int m = min(end - s0, 64);
        const int myv = perm[s0 + (lane < m ? lane : 0)];
        for (int t = 0; t < m; t += 4) {
            const int i1 = (t + 1 < m) ? t + 1 : t;
            const int i2 = (t + 2 < m) ? t + 2 : t;
            const int i3 = (t + 3 < m) ? t + 3 : t;
            const int n0 = __shfl(myv, t, 64);
            const int n1 = __shfl(myv, i1, 64);
            const int n2 = __shfl(myv, i2, 64);
            const int n3 = __shfl(myv, i3, 64);
            const ushort2 v0 = src[(size_t)n0 * 64 + lane];
            const ushort2 v1 = src[(size_t)n1 * 64 + lane];
            const ushort2 v2 = src[(size_t)n2 * 64 + lane];
            const ushort2 v3 = src[(size_t)n3 * 64 + lane];
            const float f1 = (t + 1 < m) ? 1.f : 0.f;
            const float f2 = (t + 2 < m) ? 1.f : 0.f;
            const float f3 = (t + 3 < m) ? 1.f : 0.f;
            ax += bf2f(v0.x) + f1 * bf2f(v1.x) + f2 * bf2f(v2.x) + f3 * bf2f(v3.x);
            ay += bf2f(v0.y) + f1 * bf2f(v1.y) + f2 * bf2f(v2.y) + f3 * bf2f(v3.y);
        }
    }
}

__global__ void gather_n2e_kernel(const int* __restrict__ perm, const int* __restrict__ offs,
                                  const unsigned short* __restrict__ h,
                                  unsigned short* __restrict__ ef) {
    const int wave = threadIdx.x >> 6;
    const int lane = threadIdx.x & 63;
    const int e = blockIdx.x * 4 + wave;
    const int start = offs[e], end = offs[e + 1];
    float ax = 0.f, ay = 0.f;
    gather_rows((const ushort2*)h, perm, start, end, lane, ax, ay);
    const int deg = end - start;
    const float binv = deg ? 1.f / (float)deg : 0.f;
    ushort2 o;
    o.x = f2bf(ax * binv);
    o.y = f2bf(ay * binv);
    ((ushort2*)ef)[(size_t)e * 64 + lane] = o;
}

__global__ void gather_e2n_kernel(const int* __restrict__ perm, const int* __restrict__ offs,
                                  const unsigned short* __restrict__ ef,
                                  const float* __restrict__ bias,
                                  float* __restrict__ out) {
    const int wave = threadIdx.x >> 6;
    const int lane = threadIdx.x & 63;
    const int n = blockIdx.x * 4 + wave;
    const int start = offs[n], end = offs[n + 1];
    float ax = 0.f, ay = 0.f;
    gather_rows((const ushort2*)ef, perm, start, end, lane, ax, ay);
    const int deg = end - start;
    const float dinv = deg ? 1.f / (float)deg : 0.f;
    const float2 b = ((const float2*)bias)[lane];
    float2 o;
    o.x = ax * dinv + b.x;
    o.y = ay * dinv + b.y;
    ((float2*)out)[(size_t)n * 64 + lane] = o;
}

extern "C" void kernel_launch(void* const* d_in, const int* in_sizes, int n_in,
                              void* d_out, int out_size, void* d_ws, size_t ws_size,
                              hipStream_t stream) {
    const float* x = (const float*)d_in[0];
    const float* w = (const float*)d_in[1];
    const float* bias = (const float*)d_in[2];
    const int* hei = (const int*)d_in[3];
    const int* nidx = hei;            // row 0: node indices
    const int* eidx = hei + NNZC;     // row 1: edge indices
    float* out = (float*)d_out;

    // ---- carve workspace (256B-aligned chunks), total ~92 MB ----
    char* p = (char*)d_ws;
    unsigned short* h = (unsigned short*)p;  p += (size_t)Nn * 128 * 2;      // 25.6 MB
    unsigned short* ef = (unsigned short*)p; p += (size_t)Ne * 128 * 2;      // 25.6 MB
    int* histN = (int*)p;                    p += (size_t)SCANSZ * 4;        // 800 KB
    int* histE = (int*)p;                    p += (size_t)SCANSZ * 4;        // 800 KB
    int* bsumN = (int*)p;                    p += 3328;
    int* bsumE = (int*)p;                    p += 3328;
    int* offsN = (int*)p;                    p += 400128;                    // 100001 ints
    int* offsE = (int*)p;                    p += 400128;
    int* permN = (int*)p;                    p += (size_t)NNZC * 4;          // 6.4 MB
    int* permE = (int*)p;                    p += (size_t)NNZC * 4;          // 6.4 MB
    int2* pairsN = (int2*)p;                 p += (size_t)NNZC * 8;          // 12.8 MB
    int2* pairsE = (int2*)p;                 p += (size_t)NNZC * 8;          // 12.8 MB

    // ---- dense transform (independent of CSR build) ----
    gemm_kernel<<<Nn / GROWS, 128, 0, stream>>>(x, w, h);

    // ---- bucketed CSR build, both directions fused ----
    hist_kernel<<<NBLK, 256, 0, stream>>>(nidx, eidx, histN, histE);
    scan1_kernel<<<2 * NBK, 256, 0, stream>>>(histN, histE, bsumN, bsumE);
    scan2_kernel<<<2, 1024, 0, stream>>>(bsumN, bsumE);
    scan3_kernel<<<2 * NBK, 256, 0, stream>>>(histN, histE, bsumN, bsumE);
    scatter_kernel<<<NBLK, 256, 0, stream>>>(nidx, eidx, histN, histE, pairsN, pairsE);
    fine_kernel<<<2 * NBK, BUCKW, 0, stream>>>(pairsN, pairsE, histN, histE,
                                               offsN, offsE, permN, permE);

    // ---- two gather-side segment sums ----
    gather_n2e_kernel<<<Ne / 4, 256, 0, stream>>>(permE, offsE, h, ef);
    gather_e2n_kernel<<<Nn / 4, 256, 0, stream>>>(permN, offsN, ef, bias, out);
}

// Round 4
// 337.970 us; speedup vs baseline: 17.3269x; 1.2876x over previous
//
#include <hip/hip_runtime.h>

#define Nn 100000
#define Ne 100000
#define NNZC 1600000
#define NBLK 256          // blocks for hist/scatter
#define CHUNK 6250        // NNZC / NBLK
#define BSH 7             // bucket = idx >> 7 (128 ids per bucket)
#define BUCKW 128
#define NBK 782           // ceil(100000/128)
#define SCANSZ (NBK * NBLK)  // 200192

typedef __attribute__((ext_vector_type(8))) short short8;
typedef __attribute__((ext_vector_type(4))) float floatx4;

__device__ inline float bf2f(unsigned short u) {
    union { unsigned int i; float f; } c; c.i = ((unsigned int)u) << 16; return c.f;
}
__device__ inline unsigned short f2bf(float f) {
    union { float f; unsigned int i; } c; c.f = f;
    unsigned int i = c.i;
    return (unsigned short)((i + 0x7fffu + ((i >> 16) & 1u)) >> 16);  // RNE
}
__device__ inline unsigned int f2bf2(float lo, float hi) {  // packed RNE: lo in [15:0], hi in [31:16]
    union { float f; unsigned int i; } a, b;
    a.f = lo; b.f = hi;
    const unsigned int x = (a.i + 0x7fffu + ((a.i >> 16) & 1u)) >> 16;
    const unsigned int y = (b.i + 0x7fffu + ((b.i >> 16) & 1u)) & 0xffff0000u;
    return x | y;
}

// ---- per-block bucket histograms for both directions ----
__global__ void hist_kernel(const int* __restrict__ nidx, const int* __restrict__ eidx,
                            int* __restrict__ histN, int* __restrict__ histE) {
    __shared__ int hN[NBK], hE[NBK];
    for (int j = threadIdx.x; j < NBK; j += 256) { hN[j] = 0; hE[j] = 0; }
    __syncthreads();
    const int base = blockIdx.x * CHUNK;
    for (int i = base + threadIdx.x; i < base + CHUNK; i += 256) {
        atomicAdd(&hN[nidx[i] >> BSH], 1);
        atomicAdd(&hE[eidx[i] >> BSH], 1);
    }
    __syncthreads();
    for (int j = threadIdx.x; j < NBK; j += 256) {
        histN[j * NBLK + blockIdx.x] = hN[j];   // bucket-major layout
        histE[j * NBLK + blockIdx.x] = hE[j];
    }
}

// ---- 3-phase exclusive scan over the two SCANSZ hist arrays (in place) ----
__global__ void scan1_kernel(int* __restrict__ histN, int* __restrict__ histE,
                             int* __restrict__ bsumN, int* __restrict__ bsumE) {
    const int arr = blockIdx.x / NBK;
    const int b = blockIdx.x % NBK;
    int* a = arr ? histE : histN;
    int* bs = arr ? bsumE : bsumN;
    const int t = threadIdx.x;
    int v = a[b * 256 + t];
    __shared__ int tmp[2][256];
    int pin = 0;
    tmp[0][t] = v;
    for (int off = 1; off < 256; off <<= 1) {
        __syncthreads();
        int val = tmp[pin][t];
        if (t >= off) val += tmp[pin][t - off];
        tmp[1 - pin][t] = val;
        pin ^= 1;
    }
    __syncthreads();
    int incl = tmp[pin][t];
    a[b * 256 + t] = incl - v;      // exclusive within block
    if (t == 255) bs[b] = incl;
}

__global__ void scan2_kernel(int* __restrict__ bsumN, int* __restrict__ bsumE) {
    int* bs = blockIdx.x ? bsumE : bsumN;
    const int t = threadIdx.x;  // 1024 threads
    int v = (t < NBK) ? bs[t] : 0;
    __shared__ int tmp[2][1024];
    int pin = 0;
    tmp[0][t] = v;
    for (int off = 1; off < 1024; off <<= 1) {
        __syncthreads();
        int val = tmp[pin][t];
        if (t >= off) val += tmp[pin][t - off];
        tmp[1 - pin][t] = val;
        pin ^= 1;
    }
    __syncthreads();
    if (t < NBK) bs[t] = tmp[pin][t] - v;   // exclusive block offsets
}

__global__ void scan3_kernel(int* __restrict__ histN, int* __restrict__ histE,
                             const int* __restrict__ bsumN, const int* __restrict__ bsumE) {
    const int arr = blockIdx.x / NBK;
    const int b = blockIdx.x % NBK;
    int* a = arr ? histE : histN;
    const int* bs = arr ? bsumE : bsumN;
    a[b * 256 + threadIdx.x] += bs[b];
}

// ---- scatter pairs into bucket-sorted order (block-exclusive runs) ----
__global__ void scatter_kernel(const int* __restrict__ nidx, const int* __restrict__ eidx,
                               const int* __restrict__ histN, const int* __restrict__ histE,
                               int2* __restrict__ pairsN, int2* __restrict__ pairsE) {
    __shared__ int cN[NBK], cE[NBK];
    const int blk = blockIdx.x;
    for (int j = threadIdx.x; j < NBK; j += 256) {
        cN[j] = histN[j * NBLK + blk];
        cE[j] = histE[j * NBLK + blk];
    }
    __syncthreads();
    const int base = blk * CHUNK;
    for (int i = base + threadIdx.x; i < base + CHUNK; i += 256) {
        const int n = nidx[i], e = eidx[i];
        const int pn = atomicAdd(&cN[n >> BSH], 1);
        const int pe = atomicAdd(&cE[e >> BSH], 1);
        pairsN[pn] = make_int2(n, e);   // grouped by node-bucket
        pairsE[pe] = make_int2(e, n);   // grouped by edge-bucket
    }
}

// ---- fine pass: per-bucket local counts -> per-id offsets + perm fill ----
__global__ void fine_kernel(const int2* __restrict__ pairsN, const int2* __restrict__ pairsE,
                            const int* __restrict__ histN, const int* __restrict__ histE,
                            int* __restrict__ offsN, int* __restrict__ offsE,
                            int* __restrict__ permN, int* __restrict__ permE) {
    const int arr = blockIdx.x / NBK;
    const int b = blockIdx.x % NBK;
    const int2* pairs = arr ? pairsE : pairsN;
    const int* hist = arr ? histE : histN;
    int* offs = arr ? offsE : offsN;
    int* perm = arr ? permE : permN;
    const int t = threadIdx.x;  // 128
    const int S = hist[b * NBLK];
    const int E = (b + 1 < NBK) ? hist[(b + 1) * NBLK] : NNZC;
    __shared__ int cnt[BUCKW];
    __shared__ int tmp[2][BUCKW];
    cnt[t] = 0;
    __syncthreads();
    for (int i = S + t; i < E; i += BUCKW)
        atomicAdd(&cnt[pairs[i].x & (BUCKW - 1)], 1);
    __syncthreads();
    // exclusive scan of 128 counts
    int v = cnt[t];
    int pin = 0;
    tmp[0][t] = v;
    for (int off = 1; off < BUCKW; off <<= 1) {
        __syncthreads();
        int val = tmp[pin][t];
        if (t >= off) val += tmp[pin][t - off];
        tmp[1 - pin][t] = val;
        pin ^= 1;
    }
    __syncthreads();
    const int excl = tmp[pin][t] - v;
    const int id = b * BUCKW + t;
    if (id < 100000) offs[id] = S + excl;
    if (b == NBK - 1 && t == 0) offs[100000] = NNZC;
    __syncthreads();
    cnt[t] = excl;   // reuse as cursors
    __syncthreads();
    for (int i = S + t; i < E; i += BUCKW) {
        const int2 p = pairs[i];
        const int pos = S + atomicAdd(&cnt[p.x & (BUCKW - 1)], 1);
        perm[pos] = p.y;
    }
}

// ---- h = x @ W via MFMA, bf16 output ----
// 4 waves/block, each wave one 16-row M-tile (block = 64 rows).
// W staged in LDS as Wb[n][k] bf16, row stride 136 (272 B, 16B-aligned).
__global__ __launch_bounds__(256) void gemm_mfma_kernel(const float* __restrict__ x,
                                                        const float* __restrict__ w,
                                                        unsigned short* __restrict__ h) {
    __shared__ unsigned short wlds[128 * 136];        // 34816 B
    __shared__ unsigned short tile[4][16 * 136];      // 4 x 4352 B, per-wave private
    const int tid = threadIdx.x;
    const int wave = tid >> 6, lane = tid & 63;
    const int q = lane >> 4, r16 = lane & 15;

    // stage W: w[k*128+n] fp32 -> wlds[n*136+k] bf16 (coalesced float4 reads)
    for (int i = tid; i < 4096; i += 256) {
        const int k = i >> 5;
        const int n0 = (i & 31) << 2;
        const float4 wv = *(const float4*)(w + k * 128 + n0);
        wlds[(n0 + 0) * 136 + k] = f2bf(wv.x);
        wlds[(n0 + 1) * 136 + k] = f2bf(wv.y);
        wlds[(n0 + 2) * 136 + k] = f2bf(wv.z);
        wlds[(n0 + 3) * 136 + k] = f2bf(wv.w);
    }
    __syncthreads();

    const int row0 = blockIdx.x * 64 + wave * 16;
    if (row0 >= Nn) return;   // tail waves exit (no barriers after this point)

    floatx4 acc[8];
#pragma unroll
    for (int jb = 0; jb < 8; ++jb) acc[jb] = (floatx4){0.f, 0.f, 0.f, 0.f};

    const float* ap = x + (size_t)(row0 + r16) * 128 + q * 8;
#pragma unroll
    for (int kk = 0; kk < 4; ++kk) {
        // A-frag: lane holds A[m=r16][k = kk*32 + q*8 + j], j=0..7
        const float4 a0 = *(const float4*)(ap + kk * 32);
        const float4 a1 = *(const float4*)(ap + kk * 32 + 4);
        union { unsigned int u[4]; short8 s; } af;
        af.u[0] = f2bf2(a0.x, a0.y);
        af.u[1] = f2bf2(a0.z, a0.w);
        af.u[2] = f2bf2(a1.x, a1.y);
        af.u[3] = f2bf2(a1.z, a1.w);
        const unsigned short* wp = wlds + kk * 32 + q * 8;
#pragma unroll
        for (int jb = 0; jb < 8; ++jb) {
            // B-frag: lane holds B[k = kk*32 + q*8 + j][n = jb*16 + r16]
            const short8 bfr = *(const short8*)(wp + (jb * 16 + r16) * 136);
            acc[jb] = __builtin_amdgcn_mfma_f32_16x16x32_bf16(af.s, bfr, acc[jb], 0, 0, 0);
        }
    }

    // epilogue: C/D row = q*4+r, col = jb*16+r16 -> LDS repack -> coalesced dwordx4
    unsigned short* tw = tile[wave];
#pragma unroll
    for (int jb = 0; jb < 8; ++jb)
#pragma unroll
        for (int r = 0; r < 4; ++r)
            tw[(q * 4 + r) * 136 + jb * 16 + r16] = f2bf(acc[jb][r]);

    const int rr = lane >> 2, seg = lane & 3;   // 4 lanes per row, 64 B each
    const unsigned short* src = tw + rr * 136 + seg * 32;
    unsigned short* dst = h + (size_t)(row0 + rr) * 128 + seg * 32;
    *(short8*)(dst + 0)  = *(const short8*)(src + 0);
    *(short8*)(dst + 8)  = *(const short8*)(src + 8);
    *(short8*)(dst + 16) = *(const short8*)(src + 16);
    *(short8*)(dst + 24) = *(const short8*)(src + 24);
}

// ---- gather with 4-way MLP unroll ----
__device__ inline void gather_rows(const ushort2* __restrict__ src, const int* __restrict__ perm,
                                   int start, int end, int lane, float& ax, float& ay) {
    for (int s0 = start; s0 < end; s0 += 64) {
        const int m = min(end - s0, 64);
        const int myv = perm[s0 + (lane < m ? lane : 0)];
        for (int t = 0; t < m; t += 4) {
            const int i1 = (t + 1 < m) ? t + 1 : t;
            const int i2 = (t + 2 < m) ? t + 2 : t;
            const int i3 = (t + 3 < m) ? t + 3 : t;
            const int n0 = __shfl(myv, t, 64);
            const int n1 = __shfl(myv, i1, 64);
            const int n2 = __shfl(myv, i2, 64);
            const int n3 = __shfl(myv, i3, 64);
            const ushort2 v0 = src[(size_t)n0 * 64 + lane];
            const ushort2 v1 = src[(size_t)n1 * 64 + lane];
            const ushort2 v2 = src[(size_t)n2 * 64 + lane];
            const ushort2 v3 = src[(size_t)n3 * 64 + lane];
            const float f1 = (t + 1 < m) ? 1.f : 0.f;
            const float f2 = (t + 2 < m) ? 1.f : 0.f;
            const float f3 = (t + 3 < m) ? 1.f : 0.f;
            ax += bf2f(v0.x) + f1 * bf2f(v1.x) + f2 * bf2f(v2.x) + f3 * bf2f(v3.x);
            ay += bf2f(v0.y) + f1 * bf2f(v1.y) + f2 * bf2f(v2.y) + f3 * bf2f(v3.y);
        }
    }
}

__global__ void gather_n2e_kernel(const int* __restrict__ perm, const int* __restrict__ offs,
                                  const unsigned short* __restrict__ h,
                                  unsigned short* __restrict__ ef) {
    const int wave = threadIdx.x >> 6;
    const int lane = threadIdx.x & 63;
    const int e = blockIdx.x * 4 + wave;
    const int start = offs[e], end = offs[e + 1];
    float ax = 0.f, ay = 0.f;
    gather_rows((const ushort2*)h, perm, start, end, lane, ax, ay);
    const int deg = end - start;
    const float binv = deg ? 1.f / (float)deg : 0.f;
    ushort2 o;
    o.x = f2bf(ax * binv);
    o.y = f2bf(ay * binv);
    ((ushort2*)ef)[(size_t)e * 64 + lane] = o;
}

__global__ void gather_e2n_kernel(const int* __restrict__ perm, const int* __restrict__ offs,
                                  const unsigned short* __restrict__ ef,
                                  const float* __restrict__ bias,
                                  float* __restrict__ out) {
    const int wave = threadIdx.x >> 6;
    const int lane = threadIdx.x & 63;
    const int n = blockIdx.x * 4 + wave;
    const int start = offs[n], end = offs[n + 1];
    float ax = 0.f, ay = 0.f;
    gather_rows((const ushort2*)ef, perm, start, end, lane, ax, ay);
    const int deg = end - start;
    const float dinv = deg ? 1.f / (float)deg : 0.f;
    const float2 b = ((const float2*)bias)[lane];
    float2 o;
    o.x = ax * dinv + b.x;
    o.y = ay * dinv + b.y;
    ((float2*)out)[(size_t)n * 64 + lane] = o;
}

extern "C" void kernel_launch(void* const* d_in, const int* in_sizes, int n_in,
                              void* d_out, int out_size, void* d_ws, size_t ws_size,
                              hipStream_t stream) {
    const float* x = (const float*)d_in[0];
    const float* w = (const float*)d_in[1];
    const float* bias = (const float*)d_in[2];
    const int* hei = (const int*)d_in[3];
    const int* nidx = hei;            // row 0: node indices
    const int* eidx = hei + NNZC;     // row 1: edge indices
    float* out = (float*)d_out;

    // ---- carve workspace (256B-aligned chunks), total ~92 MB ----
    char* p = (char*)d_ws;
    unsigned short* h = (unsigned short*)p;  p += (size_t)Nn * 128 * 2;      // 25.6 MB
    unsigned short* ef = (unsigned short*)p; p += (size_t)Ne * 128 * 2;      // 25.6 MB
    int* histN = (int*)p;                    p += (size_t)SCANSZ * 4;        // 800 KB
    int* histE = (int*)p;                    p += (size_t)SCANSZ * 4;        // 800 KB
    int* bsumN = (int*)p;                    p += 3328;
    int* bsumE = (int*)p;                    p += 3328;
    int* offsN = (int*)p;                    p += 400128;                    // 100001 ints
    int* offsE = (int*)p;                    p += 400128;
    int* permN = (int*)p;                    p += (size_t)NNZC * 4;          // 6.4 MB
    int* permE = (int*)p;                    p += (size_t)NNZC * 4;          // 6.4 MB
    int2* pairsN = (int2*)p;                 p += (size_t)NNZC * 8;          // 12.8 MB
    int2* pairsE = (int2*)p;                 p += (size_t)NNZC * 8;          // 12.8 MB

    // ---- dense transform (independent of CSR build) ----
    gemm_mfma_kernel<<<(Nn + 63) / 64, 256, 0, stream>>>(x, w, h);

    // ---- bucketed CSR build, both directions fused ----
    hist_kernel<<<NBLK, 256, 0, stream>>>(nidx, eidx, histN, histE);
    scan1_kernel<<<2 * NBK, 256, 0, stream>>>(histN, histE, bsumN, bsumE);
    scan2_kernel<<<2, 1024, 0, stream>>>(bsumN, bsumE);
    scan3_kernel<<<2 * NBK, 256, 0, stream>>>(histN, histE, bsumN, bsumE);
    scatter_kernel<<<NBLK, 256, 0, stream>>>(nidx, eidx, histN, histE, pairsN, pairsE);
    fine_kernel<<<2 * NBK, BUCKW, 0, stream>>>(pairsN, pairsE, histN, histE,
                                               offsN, offsE, permN, permE);

    // ---- two gather-side segment sums ----
    gather_n2e_kernel<<<Ne / 4, 256, 0, stream>>>(permE, offsE, h, ef);
    gather_e2n_kernel<<<Nn / 4, 256, 0, stream>>>(permN, offsN, ef, bias, out);
}

// Round 5
// 320.859 us; speedup vs baseline: 18.2509x; 1.0533x over previous
//
#include <hip/hip_runtime.h>

#define Nn 100000
#define Ne 100000
#define NNZC 1600000
#define NBLK 256          // blocks for hist/scatter
#define CHUNK 6250        // NNZC / NBLK
#define BSH 8             // bucket = idx >> 8 (256 ids per bucket)
#define BUCKW 256
#define NBK 391           // ceil(100000/256)

typedef __attribute__((ext_vector_type(8))) short short8;
typedef __attribute__((ext_vector_type(4))) float floatx4;

__device__ inline unsigned short f2bf(float f) {
    union { float f; unsigned int i; } c; c.f = f;
    unsigned int i = c.i;
    return (unsigned short)((i + 0x7fffu + ((i >> 16) & 1u)) >> 16);  // RNE
}
__device__ inline unsigned int f2bf2(float lo, float hi) {  // packed RNE: lo in [15:0], hi in [31:16]
    union { float f; unsigned int i; } a, b;
    a.f = lo; b.f = hi;
    const unsigned int x = (a.i + 0x7fffu + ((a.i >> 16) & 1u)) >> 16;
    const unsigned int y = (b.i + 0x7fffu + ((b.i >> 16) & 1u)) & 0xffff0000u;
    return x | y;
}

// ---- per-block bucket histograms for both directions ----
__global__ void hist_kernel(const int* __restrict__ nidx, const int* __restrict__ eidx,
                            int* __restrict__ histN, int* __restrict__ histE) {
    __shared__ int hN[NBK], hE[NBK];
    for (int j = threadIdx.x; j < NBK; j += 256) { hN[j] = 0; hE[j] = 0; }
    __syncthreads();
    const int base = blockIdx.x * CHUNK;
    for (int i = base + threadIdx.x; i < base + CHUNK; i += 256) {
        atomicAdd(&hN[nidx[i] >> BSH], 1);
        atomicAdd(&hE[eidx[i] >> BSH], 1);
    }
    __syncthreads();
    for (int j = threadIdx.x; j < NBK; j += 256) {
        histN[j * NBLK + blockIdx.x] = hN[j];   // bucket-major layout
        histE[j * NBLK + blockIdx.x] = hE[j];
    }
}

// ---- scan phase 1: exclusive scan within each bucket row (256 wide) ----
__global__ void scan1_kernel(int* __restrict__ histN, int* __restrict__ histE,
                             int* __restrict__ bsumN, int* __restrict__ bsumE) {
    const int arr = blockIdx.x / NBK;
    const int b = blockIdx.x % NBK;
    int* a = arr ? histE : histN;
    int* bs = arr ? bsumE : bsumN;
    const int t = threadIdx.x;
    int v = a[b * 256 + t];
    __shared__ int tmp[2][256];
    int pin = 0;
    tmp[0][t] = v;
    for (int off = 1; off < 256; off <<= 1) {
        __syncthreads();
        int val = tmp[pin][t];
        if (t >= off) val += tmp[pin][t - off];
        tmp[1 - pin][t] = val;
        pin ^= 1;
    }
    __syncthreads();
    int incl = tmp[pin][t];
    a[b * 256 + t] = incl - v;      // exclusive within bucket row
    if (t == 255) bs[b] = incl;
}

// ---- scan phase 2: add prefix of bucket totals (inline reduction, no scan2) ----
__global__ void scan3_kernel(int* __restrict__ histN, int* __restrict__ histE,
                             const int* __restrict__ bsumN, const int* __restrict__ bsumE) {
    const int arr = blockIdx.x / NBK;
    const int b = blockIdx.x % NBK;
    int* a = arr ? histE : histN;
    const int* bs = arr ? bsumE : bsumN;
    const int t = threadIdx.x;
    int part = 0;
    for (int i = t; i < b; i += 256) part += bs[i];
    __shared__ int red[256];
    red[t] = part;
    __syncthreads();
    for (int off = 128; off > 0; off >>= 1) {
        if (t < off) red[t] += red[t + off];
        __syncthreads();
    }
    a[b * 256 + t] += red[0];
}

// ---- scatter packed (src<<8 | local) into bucket-sorted order ----
__global__ void scatter_kernel(const int* __restrict__ nidx, const int* __restrict__ eidx,
                               const int* __restrict__ histN, const int* __restrict__ histE,
                               unsigned int* __restrict__ pairsN, unsigned int* __restrict__ pairsE) {
    __shared__ int cN[NBK], cE[NBK];
    const int blk = blockIdx.x;
    for (int j = threadIdx.x; j < NBK; j += 256) {
        cN[j] = histN[j * NBLK + blk];
        cE[j] = histE[j * NBLK + blk];
    }
    __syncthreads();
    const int base = blk * CHUNK;
    for (int i = base + threadIdx.x; i < base + CHUNK; i += 256) {
        const int n = nidx[i], e = eidx[i];
        const int pn = atomicAdd(&cN[n >> BSH], 1);
        const int pe = atomicAdd(&cE[e >> BSH], 1);
        pairsN[pn] = ((unsigned int)e << 8) | (unsigned int)(n & 255);  // node-bucket sorted
        pairsE[pe] = ((unsigned int)n << 8) | (unsigned int)(e & 255);  // edge-bucket sorted
    }
}

// ---- fine pass: per-bucket local counting sort -> offs + perm ----
__global__ void fine_kernel(const unsigned int* __restrict__ pairsN, const unsigned int* __restrict__ pairsE,
                            const int* __restrict__ histN, const int* __restrict__ histE,
                            int* __restrict__ offsN, int* __restrict__ offsE,
                            int* __restrict__ permN, int* __restrict__ permE) {
    const int arr = blockIdx.x / NBK;
    const int b = blockIdx.x % NBK;
    const unsigned int* pairs = arr ? pairsE : pairsN;
    const int* hist = arr ? histE : histN;
    int* offs = arr ? offsE : offsN;
    int* perm = arr ? permE : permN;
    const int t = threadIdx.x;  // 256
    const int S = hist[b * NBLK];
    const int E = (b + 1 < NBK) ? hist[(b + 1) * NBLK] : NNZC;
    __shared__ int cnt[BUCKW];
    __shared__ int tmp[2][BUCKW];
    cnt[t] = 0;
    __syncthreads();
    for (int i = S + t; i < E; i += BUCKW)
        atomicAdd(&cnt[pairs[i] & 255u], 1);
    __syncthreads();
    int v = cnt[t];
    int pin = 0;
    tmp[0][t] = v;
    for (int off = 1; off < BUCKW; off <<= 1) {
        __syncthreads();
        int val = tmp[pin][t];
        if (t >= off) val += tmp[pin][t - off];
        tmp[1 - pin][t] = val;
        pin ^= 1;
    }
    __syncthreads();
    const int excl = tmp[pin][t] - v;
    const int id = b * BUCKW + t;
    if (id < 100000) offs[id] = S + excl;
    if (b == NBK - 1 && t == 0) offs[100000] = NNZC;
    __syncthreads();
    cnt[t] = excl;   // reuse as cursors
    __syncthreads();
    for (int i = S + t; i < E; i += BUCKW) {
        const unsigned int p = pairs[i];
        const int pos = S + atomicAdd(&cnt[p & 255u], 1);
        perm[pos] = (int)(p >> 8);
    }
}

// ---- h = x @ W via MFMA, bf16 output ----
__global__ __launch_bounds__(256) void gemm_mfma_kernel(const float* __restrict__ x,
                                                        const float* __restrict__ w,
                                                        unsigned short* __restrict__ h) {
    __shared__ unsigned short wlds[128 * 136];        // 34816 B
    __shared__ unsigned short tile[4][16 * 136];      // per-wave private
    const int tid = threadIdx.x;
    const int wave = tid >> 6, lane = tid & 63;
    const int q = lane >> 4, r16 = lane & 15;

    for (int i = tid; i < 4096; i += 256) {
        const int k = i >> 5;
        const int n0 = (i & 31) << 2;
        const float4 wv = *(const float4*)(w + k * 128 + n0);
        wlds[(n0 + 0) * 136 + k] = f2bf(wv.x);
        wlds[(n0 + 1) * 136 + k] = f2bf(wv.y);
        wlds[(n0 + 2) * 136 + k] = f2bf(wv.z);
        wlds[(n0 + 3) * 136 + k] = f2bf(wv.w);
    }
    __syncthreads();

    const int row0 = blockIdx.x * 64 + wave * 16;
    if (row0 >= Nn) return;

    floatx4 acc[8];
#pragma unroll
    for (int jb = 0; jb < 8; ++jb) acc[jb] = (floatx4){0.f, 0.f, 0.f, 0.f};

    const float* ap = x + (size_t)(row0 + r16) * 128 + q * 8;
#pragma unroll
    for (int kk = 0; kk < 4; ++kk) {
        const float4 a0 = *(const float4*)(ap + kk * 32);
        const float4 a1 = *(const float4*)(ap + kk * 32 + 4);
        union { unsigned int u[4]; short8 s; } af;
        af.u[0] = f2bf2(a0.x, a0.y);
        af.u[1] = f2bf2(a0.z, a0.w);
        af.u[2] = f2bf2(a1.x, a1.y);
        af.u[3] = f2bf2(a1.z, a1.w);
        const unsigned short* wp = wlds + kk * 32 + q * 8;
#pragma unroll
        for (int jb = 0; jb < 8; ++jb) {
            const short8 bfr = *(const short8*)(wp + (jb * 16 + r16) * 136);
            acc[jb] = __builtin_amdgcn_mfma_f32_16x16x32_bf16(af.s, bfr, acc[jb], 0, 0, 0);
        }
    }

    unsigned short* tw = tile[wave];
#pragma unroll
    for (int jb = 0; jb < 8; ++jb)
#pragma unroll
        for (int r = 0; r < 4; ++r)
            tw[(q * 4 + r) * 136 + jb * 16 + r16] = f2bf(acc[jb][r]);

    const int rr = lane >> 2, seg = lane & 3;
    const unsigned short* src = tw + rr * 136 + seg * 32;
    unsigned short* dst = h + (size_t)(row0 + rr) * 128 + seg * 32;
    *(short8*)(dst + 0)  = *(const short8*)(src + 0);
    *(short8*)(dst + 8)  = *(const short8*)(src + 8);
    *(short8*)(dst + 16) = *(const short8*)(src + 16);
    *(short8*)(dst + 24) = *(const short8*)(src + 24);
}

// ---- gather inner loop: tail-free quads, 32-bit saddr addressing ----
__device__ inline void gather_rows(const char* __restrict__ src, const int* __restrict__ perm,
                                   int start, int end, int lane, float& ax, float& ay) {
    const unsigned int laneoff = (unsigned int)lane << 2;
    for (int s0 = start; s0 < end; s0 += 64) {
        const int m = min(end - s0, 64);
        const int myv = perm[s0 + (lane < m ? lane : 0)];
        int t = 0;
        for (; t + 3 < m; t += 4) {
            const unsigned int a0 = ((unsigned int)__shfl(myv, t, 64) << 8) | laneoff;
            const unsigned int a1 = ((unsigned int)__shfl(myv, t + 1, 64) << 8) | laneoff;
            const unsigned int a2 = ((unsigned int)__shfl(myv, t + 2, 64) << 8) | laneoff;
            const unsigned int a3 = ((unsigned int)__shfl(myv, t + 3, 64) << 8) | laneoff;
            const unsigned int u0 = *(const unsigned int*)(src + a0);
            const unsigned int u1 = *(const unsigned int*)(src + a1);
            const unsigned int u2 = *(const unsigned int*)(src + a2);
            const unsigned int u3 = *(const unsigned int*)(src + a3);
            ax += __uint_as_float(u0 << 16); ay += __uint_as_float(u0 & 0xffff0000u);
            ax += __uint_as_float(u1 << 16); ay += __uint_as_float(u1 & 0xffff0000u);
            ax += __uint_as_float(u2 << 16); ay += __uint_as_float(u2 & 0xffff0000u);
            ax += __uint_as_float(u3 << 16); ay += __uint_as_float(u3 & 0xffff0000u);
        }
        for (; t < m; ++t) {
            const unsigned int a0 = ((unsigned int)__shfl(myv, t, 64) << 8) | laneoff;
            const unsigned int u0 = *(const unsigned int*)(src + a0);
            ax += __uint_as_float(u0 << 16); ay += __uint_as_float(u0 & 0xffff0000u);
        }
    }
}

__global__ void gather_n2e_kernel(const int* __restrict__ perm, const int* __restrict__ offs,
                                  const unsigned short* __restrict__ h,
                                  unsigned short* __restrict__ ef) {
    const int wave = threadIdx.x >> 6;
    const int lane = threadIdx.x & 63;
    const int e = blockIdx.x * 4 + wave;
    const int start = offs[e], end = offs[e + 1];
    float ax = 0.f, ay = 0.f;
    gather_rows((const char*)h, perm, start, end, lane, ax, ay);
    const int deg = end - start;
    const float binv = deg ? 1.f / (float)deg : 0.f;
    const unsigned int o = f2bf2(ax * binv, ay * binv);
    *(unsigned int*)((char*)ef + (((unsigned int)e << 8) | ((unsigned int)lane << 2))) = o;
}

__global__ void gather_e2n_kernel(const int* __restrict__ perm, const int* __restrict__ offs,
                                  const unsigned short* __restrict__ ef,
                                  const float* __restrict__ bias,
                                  float* __restrict__ out) {
    const int wave = threadIdx.x >> 6;
    const int lane = threadIdx.x & 63;
    const int n = blockIdx.x * 4 + wave;
    const int start = offs[n], end = offs[n + 1];
    float ax = 0.f, ay = 0.f;
    gather_rows((const char*)ef, perm, start, end, lane, ax, ay);
    const int deg = end - start;
    const float dinv = deg ? 1.f / (float)deg : 0.f;
    const float2 b = ((const float2*)bias)[lane];
    float2 o;
    o.x = ax * dinv + b.x;
    o.y = ay * dinv + b.y;
    *(float2*)((char*)out + (((unsigned int)n << 9) | ((unsigned int)lane << 3))) = o;
}

extern "C" void kernel_launch(void* const* d_in, const int* in_sizes, int n_in,
                              void* d_out, int out_size, void* d_ws, size_t ws_size,
                              hipStream_t stream) {
    const float* x = (const float*)d_in[0];
    const float* w = (const float*)d_in[1];
    const float* bias = (const float*)d_in[2];
    const int* hei = (const int*)d_in[3];
    const int* nidx = hei;            // row 0: node indices
    const int* eidx = hei + NNZC;     // row 1: edge indices
    float* out = (float*)d_out;

    // ---- carve workspace (256B-aligned chunks), ~79 MB ----
    char* p = (char*)d_ws;
    unsigned short* h = (unsigned short*)p;  p += (size_t)Nn * 128 * 2;      // 25.6 MB
    unsigned short* ef = (unsigned short*)p; p += (size_t)Ne * 128 * 2;      // 25.6 MB
    int* histN = (int*)p;                    p += (size_t)NBK * NBLK * 4 + 256;
    int* histE = (int*)p;                    p += (size_t)NBK * NBLK * 4 + 256;
    int* bsumN = (int*)p;                    p += 1792;
    int* bsumE = (int*)p;                    p += 1792;
    int* offsN = (int*)p;                    p += 400128;                    // 100001 ints
    int* offsE = (int*)p;                    p += 400128;
    int* permN = (int*)p;                    p += (size_t)NNZC * 4;          // 6.4 MB
    int* permE = (int*)p;                    p += (size_t)NNZC * 4;          // 6.4 MB
    unsigned int* pairsN = (unsigned int*)p; p += (size_t)NNZC * 4;          // 6.4 MB
    unsigned int* pairsE = (unsigned int*)p; p += (size_t)NNZC * 4;          // 6.4 MB

    // ---- dense transform ----
    gemm_mfma_kernel<<<(Nn + 63) / 64, 256, 0, stream>>>(x, w, h);

    // ---- bucketed CSR build, both directions fused ----
    hist_kernel<<<NBLK, 256, 0, stream>>>(nidx, eidx, histN, histE);
    scan1_kernel<<<2 * NBK, 256, 0, stream>>>(histN, histE, bsumN, bsumE);
    scan3_kernel<<<2 * NBK, 256, 0, stream>>>(histN, histE, bsumN, bsumE);
    scatter_kernel<<<NBLK, 256, 0, stream>>>(nidx, eidx, histN, histE, pairsN, pairsE);
    fine_kernel<<<2 * NBK, BUCKW, 0, stream>>>(pairsN, pairsE, histN, histE,
                                               offsN, offsE, permN, permE);

    // ---- two gather-side segment sums ----
    gather_n2e_kernel<<<Ne / 4, 256, 0, stream>>>(permE, offsE, h, ef);
    gather_e2n_kernel<<<Nn / 4, 256, 0, stream>>>(permN, offsN, ef, bias, out);
}

// Round 6
// 313.076 us; speedup vs baseline: 18.7046x; 1.0249x over previous
//
#include <hip/hip_runtime.h>

#define Nn 100000
#define Ne 100000
#define NNZC 1600000
#define NBLK 256          // blocks for hist/scatter
#define CHUNK 6250        // NNZC / NBLK
#define BSH 8             // bucket = idx >> 8 (256 ids per bucket)
#define BUCKW 256
#define NBK 391           // ceil(100000/256)
#define GEMM_BLOCKS 1563  // ceil(100000/64)

typedef __attribute__((ext_vector_type(8))) short short8;
typedef __attribute__((ext_vector_type(4))) float floatx4;

__device__ inline unsigned short f2bf(float f) {
    union { float f; unsigned int i; } c; c.f = f;
    unsigned int i = c.i;
    return (unsigned short)((i + 0x7fffu + ((i >> 16) & 1u)) >> 16);  // RNE
}
__device__ inline unsigned int f2bf2(float lo, float hi) {  // packed RNE
    union { float f; unsigned int i; } a, b;
    a.f = lo; b.f = hi;
    const unsigned int x = (a.i + 0x7fffu + ((a.i >> 16) & 1u)) >> 16;
    const unsigned int y = (b.i + 0x7fffu + ((b.i >> 16) & 1u)) & 0xffff0000u;
    return x | y;
}

// ---- per-block bucket histograms for both directions ----
__global__ void hist_kernel(const int* __restrict__ nidx, const int* __restrict__ eidx,
                            int* __restrict__ histN, int* __restrict__ histE) {
    __shared__ int hN[NBK], hE[NBK];
    for (int j = threadIdx.x; j < NBK; j += 256) { hN[j] = 0; hE[j] = 0; }
    __syncthreads();
    const int base = blockIdx.x * CHUNK;
    for (int i = base + threadIdx.x; i < base + CHUNK; i += 256) {
        atomicAdd(&hN[nidx[i] >> BSH], 1);
        atomicAdd(&hE[eidx[i] >> BSH], 1);
    }
    __syncthreads();
    for (int j = threadIdx.x; j < NBK; j += 256) {
        histN[j * NBLK + blockIdx.x] = hN[j];   // bucket-major layout
        histE[j * NBLK + blockIdx.x] = hE[j];
    }
}

// ---- scan phase 1: exclusive scan within each bucket row (256 wide) ----
__global__ void scan1_kernel(int* __restrict__ histN, int* __restrict__ histE,
                             int* __restrict__ bsumN, int* __restrict__ bsumE) {
    const int arr = blockIdx.x / NBK;
    const int b = blockIdx.x % NBK;
    int* a = arr ? histE : histN;
    int* bs = arr ? bsumE : bsumN;
    const int t = threadIdx.x;
    int v = a[b * 256 + t];
    __shared__ int tmp[2][256];
    int pin = 0;
    tmp[0][t] = v;
    for (int off = 1; off < 256; off <<= 1) {
        __syncthreads();
        int val = tmp[pin][t];
        if (t >= off) val += tmp[pin][t - off];
        tmp[1 - pin][t] = val;
        pin ^= 1;
    }
    __syncthreads();
    int incl = tmp[pin][t];
    a[b * 256 + t] = incl - v;      // exclusive within bucket row
    if (t == 255) bs[b] = incl;
}

// ---- scan phase 2: add prefix of bucket totals ----
__global__ void scan3_kernel(int* __restrict__ histN, int* __restrict__ histE,
                             const int* __restrict__ bsumN, const int* __restrict__ bsumE) {
    const int arr = blockIdx.x / NBK;
    const int b = blockIdx.x % NBK;
    int* a = arr ? histE : histN;
    const int* bs = arr ? bsumE : bsumN;
    const int t = threadIdx.x;
    int part = 0;
    for (int i = t; i < b; i += 256) part += bs[i];
    __shared__ int red[256];
    red[t] = part;
    __syncthreads();
    for (int off = 128; off > 0; off >>= 1) {
        if (t < off) red[t] += red[t + off];
        __syncthreads();
    }
    a[b * 256 + t] += red[0];
}

// ---- fused: gemm (blocks [0,GEMM_BLOCKS)) + scatter (blocks >= GEMM_BLOCKS) ----
__global__ __launch_bounds__(256) void gemm_scatter_kernel(
        const float* __restrict__ x, const float* __restrict__ w,
        unsigned short* __restrict__ h,
        const int* __restrict__ nidx, const int* __restrict__ eidx,
        const int* __restrict__ histN, const int* __restrict__ histE,
        unsigned int* __restrict__ pairsN, unsigned int* __restrict__ pairsE) {
    __shared__ union {
        struct { unsigned short wlds[128 * 136]; unsigned short tile[4][16 * 136]; } g;
        struct { int cN[NBK]; int cE[NBK]; } s;
    } sm;
    const int tid = threadIdx.x;

    if (blockIdx.x < GEMM_BLOCKS) {
        // ================= GEMM: h = bf16(x @ W) =================
        const int wave = tid >> 6, lane = tid & 63;
        const int q = lane >> 4, r16 = lane & 15;

        for (int i = tid; i < 4096; i += 256) {
            const int k = i >> 5;
            const int n0 = (i & 31) << 2;
            const float4 wv = *(const float4*)(w + k * 128 + n0);
            sm.g.wlds[(n0 + 0) * 136 + k] = f2bf(wv.x);
            sm.g.wlds[(n0 + 1) * 136 + k] = f2bf(wv.y);
            sm.g.wlds[(n0 + 2) * 136 + k] = f2bf(wv.z);
            sm.g.wlds[(n0 + 3) * 136 + k] = f2bf(wv.w);
        }
        __syncthreads();

        const int row0 = blockIdx.x * 64 + wave * 16;
        if (row0 >= Nn) return;   // tail waves exit (no barriers after)

        floatx4 acc[8];
#pragma unroll
        for (int jb = 0; jb < 8; ++jb) acc[jb] = (floatx4){0.f, 0.f, 0.f, 0.f};

        const float* ap = x + (size_t)(row0 + r16) * 128 + q * 8;
#pragma unroll
        for (int kk = 0; kk < 4; ++kk) {
            const float4 a0 = *(const float4*)(ap + kk * 32);
            const float4 a1 = *(const float4*)(ap + kk * 32 + 4);
            union { unsigned int u[4]; short8 s; } af;
            af.u[0] = f2bf2(a0.x, a0.y);
            af.u[1] = f2bf2(a0.z, a0.w);
            af.u[2] = f2bf2(a1.x, a1.y);
            af.u[3] = f2bf2(a1.z, a1.w);
            const unsigned short* wp = sm.g.wlds + kk * 32 + q * 8;
#pragma unroll
            for (int jb = 0; jb < 8; ++jb) {
                const short8 bfr = *(const short8*)(wp + (jb * 16 + r16) * 136);
                acc[jb] = __builtin_amdgcn_mfma_f32_16x16x32_bf16(af.s, bfr, acc[jb], 0, 0, 0);
            }
        }

        unsigned short* tw = sm.g.tile[wave];
#pragma unroll
        for (int jb = 0; jb < 8; ++jb)
#pragma unroll
            for (int r = 0; r < 4; ++r)
                tw[(q * 4 + r) * 136 + jb * 16 + r16] = f2bf(acc[jb][r]);

        const int rr = lane >> 2, seg = lane & 3;
        const unsigned short* src = tw + rr * 136 + seg * 32;
        unsigned short* dst = h + (size_t)(row0 + rr) * 128 + seg * 32;
        *(short8*)(dst + 0)  = *(const short8*)(src + 0);
        *(short8*)(dst + 8)  = *(const short8*)(src + 8);
        *(short8*)(dst + 16) = *(const short8*)(src + 16);
        *(short8*)(dst + 24) = *(const short8*)(src + 24);
    } else {
        // ================= SCATTER: bucket-sort packed pairs =================
        const int blk = blockIdx.x - GEMM_BLOCKS;
        for (int j = tid; j < NBK; j += 256) {
            sm.s.cN[j] = histN[j * NBLK + blk];
            sm.s.cE[j] = histE[j * NBLK + blk];
        }
        __syncthreads();
        const int base = blk * CHUNK;
        for (int i = base + tid; i < base + CHUNK; i += 256) {
            const int n = nidx[i], e = eidx[i];
            const int pn = atomicAdd(&sm.s.cN[n >> BSH], 1);
            const int pe = atomicAdd(&sm.s.cE[e >> BSH], 1);
            pairsN[pn] = ((unsigned int)e << 8) | (unsigned int)(n & 255);
            pairsE[pe] = ((unsigned int)n << 8) | (unsigned int)(e & 255);
        }
    }
}

// ---- fine pass: per-bucket local counting sort -> offs + perm ----
__global__ void fine_kernel(const unsigned int* __restrict__ pairsN, const unsigned int* __restrict__ pairsE,
                            const int* __restrict__ histN, const int* __restrict__ histE,
                            int* __restrict__ offsN, int* __restrict__ offsE,
                            int* __restrict__ permN, int* __restrict__ permE) {
    const int arr = blockIdx.x / NBK;
    const int b = blockIdx.x % NBK;
    const unsigned int* pairs = arr ? pairsE : pairsN;
    const int* hist = arr ? histE : histN;
    int* offs = arr ? offsE : offsN;
    int* perm = arr ? permE : permN;
    const int t = threadIdx.x;  // 256
    const int S = hist[b * NBLK];
    const int E = (b + 1 < NBK) ? hist[(b + 1) * NBLK] : NNZC;
    __shared__ int cnt[BUCKW];
    __shared__ int tmp[2][BUCKW];
    cnt[t] = 0;
    __syncthreads();
    for (int i = S + t; i < E; i += BUCKW)
        atomicAdd(&cnt[pairs[i] & 255u], 1);
    __syncthreads();
    int v = cnt[t];
    int pin = 0;
    tmp[0][t] = v;
    for (int off = 1; off < BUCKW; off <<= 1) {
        __syncthreads();
        int val = tmp[pin][t];
        if (t >= off) val += tmp[pin][t - off];
        tmp[1 - pin][t] = val;
        pin ^= 1;
    }
    __syncthreads();
    const int excl = tmp[pin][t] - v;
    const int id = b * BUCKW + t;
    if (id < 100000) offs[id] = S + excl;
    if (b == NBK - 1 && t == 0) offs[100000] = NNZC;
    __syncthreads();
    cnt[t] = excl;   // reuse as cursors
    __syncthreads();
    for (int i = S + t; i < E; i += BUCKW) {
        const unsigned int p = pairs[i];
        const int pos = S + atomicAdd(&cnt[p & 255u], 1);
        perm[pos] = (int)(p >> 8);
    }
}

// ---- gather inner loop: 8 loads in flight, masked tail group ----
__device__ inline void gather_rows(const char* __restrict__ src, const int* __restrict__ perm,
                                   int start, int end, int lane, float& ax, float& ay) {
    const unsigned int laneoff = (unsigned int)lane << 2;
    for (int s0 = start; s0 < end; s0 += 64) {
        const int m = min(end - s0, 64);
        const int myv = perm[s0 + (lane < m ? lane : 0)];
        int t = 0;
        for (; t + 7 < m; t += 8) {
            unsigned int a[8], u[8];
#pragma unroll
            for (int j = 0; j < 8; ++j)
                a[j] = ((unsigned int)__shfl(myv, t + j, 64) << 8) | laneoff;
#pragma unroll
            for (int j = 0; j < 8; ++j) u[j] = *(const unsigned int*)(src + a[j]);
#pragma unroll
            for (int j = 0; j < 8; ++j) {
                ax += __uint_as_float(u[j] << 16);
                ay += __uint_as_float(u[j] & 0xffff0000u);
            }
        }
        if (t < m) {  // masked 8-group tail: all loads stay in flight
            unsigned int a[8], u[8];
            float f[8];
#pragma unroll
            for (int j = 0; j < 8; ++j) {
                const int idx = (t + j < m) ? t + j : t;
                f[j] = (t + j < m) ? 1.f : 0.f;
                a[j] = ((unsigned int)__shfl(myv, idx, 64) << 8) | laneoff;
            }
#pragma unroll
            for (int j = 0; j < 8; ++j) u[j] = *(const unsigned int*)(src + a[j]);
#pragma unroll
            for (int j = 0; j < 8; ++j) {
                ax += f[j] * __uint_as_float(u[j] << 16);
                ay += f[j] * __uint_as_float(u[j] & 0xffff0000u);
            }
        }
    }
}

__global__ void gather_n2e_kernel(const int* __restrict__ perm, const int* __restrict__ offs,
                                  const unsigned short* __restrict__ h,
                                  unsigned short* __restrict__ ef) {
    const int wave = threadIdx.x >> 6;
    const int lane = threadIdx.x & 63;
    const int e = blockIdx.x * 4 + wave;
    const int start = offs[e], end = offs[e + 1];
    float ax = 0.f, ay = 0.f;
    gather_rows((const char*)h, perm, start, end, lane, ax, ay);
    const int deg = end - start;
    const float binv = deg ? 1.f / (float)deg : 0.f;
    const unsigned int o = f2bf2(ax * binv, ay * binv);
    *(unsigned int*)((char*)ef + (((unsigned int)e << 8) | ((unsigned int)lane << 2))) = o;
}

__global__ void gather_e2n_kernel(const int* __restrict__ perm, const int* __restrict__ offs,
                                  const unsigned short* __restrict__ ef,
                                  const float* __restrict__ bias,
                                  float* __restrict__ out) {
    const int wave = threadIdx.x >> 6;
    const int lane = threadIdx.x & 63;
    const int n = blockIdx.x * 4 + wave;
    const int start = offs[n], end = offs[n + 1];
    float ax = 0.f, ay = 0.f;
    gather_rows((const char*)ef, perm, start, end, lane, ax, ay);
    const int deg = end - start;
    const float dinv = deg ? 1.f / (float)deg : 0.f;
    const float2 b = ((const float2*)bias)[lane];
    float2 o;
    o.x = ax * dinv + b.x;
    o.y = ay * dinv + b.y;
    *(float2*)((char*)out + (((unsigned int)n << 9) | ((unsigned int)lane << 3))) = o;
}

extern "C" void kernel_launch(void* const* d_in, const int* in_sizes, int n_in,
                              void* d_out, int out_size, void* d_ws, size_t ws_size,
                              hipStream_t stream) {
    const float* x = (const float*)d_in[0];
    const float* w = (const float*)d_in[1];
    const float* bias = (const float*)d_in[2];
    const int* hei = (const int*)d_in[3];
    const int* nidx = hei;            // row 0: node indices
    const int* eidx = hei + NNZC;     // row 1: edge indices
    float* out = (float*)d_out;

    // ---- carve workspace (256B-aligned chunks), ~79 MB ----
    char* p = (char*)d_ws;
    unsigned short* h = (unsigned short*)p;  p += (size_t)Nn * 128 * 2;      // 25.6 MB
    unsigned short* ef = (unsigned short*)p; p += (size_t)Ne * 128 * 2;      // 25.6 MB
    int* histN = (int*)p;                    p += (size_t)NBK * NBLK * 4 + 256;
    int* histE = (int*)p;                    p += (size_t)NBK * NBLK * 4 + 256;
    int* bsumN = (int*)p;                    p += 1792;
    int* bsumE = (int*)p;                    p += 1792;
    int* offsN = (int*)p;                    p += 400128;                    // 100001 ints
    int* offsE = (int*)p;                    p += 400128;
    int* permN = (int*)p;                    p += (size_t)NNZC * 4;          // 6.4 MB
    int* permE = (int*)p;                    p += (size_t)NNZC * 4;          // 6.4 MB
    unsigned int* pairsN = (unsigned int*)p; p += (size_t)NNZC * 4;          // 6.4 MB
    unsigned int* pairsE = (unsigned int*)p; p += (size_t)NNZC * 4;          // 6.4 MB

    // ---- bucketed CSR build; gemm fused with scatter (independent work) ----
    hist_kernel<<<NBLK, 256, 0, stream>>>(nidx, eidx, histN, histE);
    scan1_kernel<<<2 * NBK, 256, 0, stream>>>(histN, histE, bsumN, bsumE);
    scan3_kernel<<<2 * NBK, 256, 0, stream>>>(histN, histE, bsumN, bsumE);
    gemm_scatter_kernel<<<GEMM_BLOCKS + NBLK, 256, 0, stream>>>(
        x, w, h, nidx, eidx, histN, histE, pairsN, pairsE);
    fine_kernel<<<2 * NBK, BUCKW, 0, stream>>>(pairsN, pairsE, histN, histE,
                                               offsN, offsE, permN, permE);

    // ---- two gather-side segment sums ----
    gather_n2e_kernel<<<Ne / 4, 256, 0, stream>>>(permE, offsE, h, ef);
    gather_e2n_kernel<<<Nn / 4, 256, 0, stream>>>(permN, offsN, ef, bias, out);
}

// Round 7
// 299.834 us; speedup vs baseline: 19.5307x; 1.0442x over previous
//
#include <hip/hip_runtime.h>

#define Nn 100000
#define Ne 100000
#define NNZC 1600000
#define NBLK 256          // blocks for hist/scatter
#define CHUNK 6250        // NNZC / NBLK
#define BSH 8             // bucket = idx >> 8 (256 ids per bucket)
#define BUCKW 256
#define NBK 391           // ceil(100000/256)
#define GEMM_TOTAL 1563   // ceil(100000/64)
#define GEMM_A 782        // gemm blocks fused with hist
#define GEMM_B 781        // gemm blocks fused with scatter
#define FCAP 5888         // fine-pass LDS pair cache (23.5 KB; segments ~4096+-64)

typedef __attribute__((ext_vector_type(8))) short short8;
typedef __attribute__((ext_vector_type(4))) float floatx4;

__device__ inline unsigned short f2bf(float f) {
    union { float f; unsigned int i; } c; c.f = f;
    unsigned int i = c.i;
    return (unsigned short)((i + 0x7fffu + ((i >> 16) & 1u)) >> 16);  // RNE
}
__device__ inline unsigned int f2bf2(float lo, float hi) {  // packed RNE
    union { float f; unsigned int i; } a, b;
    a.f = lo; b.f = hi;
    const unsigned int x = (a.i + 0x7fffu + ((a.i >> 16) & 1u)) >> 16;
    const unsigned int y = (b.i + 0x7fffu + ((b.i >> 16) & 1u)) & 0xffff0000u;
    return x | y;
}

// shared-memory union for the two fused kernels
union FusedLds {
    unsigned short wlds[128 * 136];           // 34816 B (gemm W staging)
    struct { int a[NBK]; int b[NBK]; } s;     // 3128 B (hist/scatter cursors)
};

// ---- gemm block body: h[64 rows] = bf16(x @ W), operand-swapped MFMA ----
// D = Wfrag(A-op) * xfrag(B-op): lane holds h[row0+r16][jb*16+q*4+r] -> direct stores.
__device__ inline void gemm_block(int gb, const float* __restrict__ x,
                                  const float* __restrict__ w,
                                  unsigned short* __restrict__ h,
                                  unsigned short* wlds, int tid) {
    const int wave = tid >> 6, lane = tid & 63;
    const int q = lane >> 4, r16 = lane & 15;

    // stage W: w[k*128+n] fp32 -> wlds[n*136+k] bf16
    for (int i = tid; i < 4096; i += 256) {
        const int k = i >> 5;
        const int n0 = (i & 31) << 2;
        const float4 wv = *(const float4*)(w + k * 128 + n0);
        wlds[(n0 + 0) * 136 + k] = f2bf(wv.x);
        wlds[(n0 + 1) * 136 + k] = f2bf(wv.y);
        wlds[(n0 + 2) * 136 + k] = f2bf(wv.z);
        wlds[(n0 + 3) * 136 + k] = f2bf(wv.w);
    }
    __syncthreads();

    const int row0 = gb * 64 + wave * 16;
    const int rrow = min(row0 + r16, Nn - 1);   // clamp: x ends on a page boundary

    floatx4 acc[8];
#pragma unroll
    for (int jb = 0; jb < 8; ++jb) acc[jb] = (floatx4){0.f, 0.f, 0.f, 0.f};

    const float* ap = x + (size_t)rrow * 128 + q * 8;
#pragma unroll
    for (int kk = 0; kk < 4; ++kk) {
        // x fragment = B-operand: B[k=q*8+j][m=r16]
        const float4 a0 = *(const float4*)(ap + kk * 32);
        const float4 a1 = *(const float4*)(ap + kk * 32 + 4);
        union { unsigned int u[4]; short8 s; } xf;
        xf.u[0] = f2bf2(a0.x, a0.y);
        xf.u[1] = f2bf2(a0.z, a0.w);
        xf.u[2] = f2bf2(a1.x, a1.y);
        xf.u[3] = f2bf2(a1.z, a1.w);
        const unsigned short* wp = wlds + kk * 32 + q * 8;
#pragma unroll
        for (int jb = 0; jb < 8; ++jb) {
            // W fragment = A-operand: A[n=r16 (within jb)][k=q*8+j]
            const short8 wf = *(const short8*)(wp + (jb * 16 + r16) * 136);
            acc[jb] = __builtin_amdgcn_mfma_f32_16x16x32_bf16(wf, xf.s, acc[jb], 0, 0, 0);
        }
    }

    // lane holds h[row0+r16][jb*16 + q*4 + r] -> 8 x 8B stores, no LDS round-trip
    if (row0 + r16 < Nn) {
        unsigned short* hb = h + (size_t)(row0 + r16) * 128 + q * 4;
#pragma unroll
        for (int jb = 0; jb < 8; ++jb) {
            uint2 o;
            o.x = f2bf2(acc[jb][0], acc[jb][1]);
            o.y = f2bf2(acc[jb][2], acc[jb][3]);
            *(uint2*)(hb + jb * 16) = o;
        }
    }
}

// ---- fused: hist (blocks [0,NBLK)) + gemm blocks [0, GEMM_A) ----
__global__ __launch_bounds__(256) void hist_gemm_kernel(
        const int* __restrict__ nidx, const int* __restrict__ eidx,
        int* __restrict__ histN, int* __restrict__ histE,
        const float* __restrict__ x, const float* __restrict__ w,
        unsigned short* __restrict__ h) {
    __shared__ FusedLds sm;
    const int tid = threadIdx.x;
    if (blockIdx.x < NBLK) {
        for (int j = tid; j < NBK; j += 256) { sm.s.a[j] = 0; sm.s.b[j] = 0; }
        __syncthreads();
        const int base = blockIdx.x * CHUNK;
        for (int i = base + tid; i < base + CHUNK; i += 256) {
            atomicAdd(&sm.s.a[nidx[i] >> BSH], 1);
            atomicAdd(&sm.s.b[eidx[i] >> BSH], 1);
        }
        __syncthreads();
        for (int j = tid; j < NBK; j += 256) {
            histN[j * NBLK + blockIdx.x] = sm.s.a[j];
            histE[j * NBLK + blockIdx.x] = sm.s.b[j];
        }
    } else {
        gemm_block(blockIdx.x - NBLK, x, w, h, sm.wlds, tid);
    }
}

// ---- scan phase 1: exclusive scan within each bucket row (256 wide) ----
__global__ void scan1_kernel(int* __restrict__ histN, int* __restrict__ histE,
                             int* __restrict__ bsumN, int* __restrict__ bsumE) {
    const int arr = blockIdx.x / NBK;
    const int b = blockIdx.x % NBK;
    int* a = arr ? histE : histN;
    int* bs = arr ? bsumE : bsumN;
    const int t = threadIdx.x;
    int v = a[b * 256 + t];
    __shared__ int tmp[2][256];
    int pin = 0;
    tmp[0][t] = v;
    for (int off = 1; off < 256; off <<= 1) {
        __syncthreads();
        int val = tmp[pin][t];
        if (t >= off) val += tmp[pin][t - off];
        tmp[1 - pin][t] = val;
        pin ^= 1;
    }
    __syncthreads();
    int incl = tmp[pin][t];
    a[b * 256 + t] = incl - v;      // exclusive within bucket row
    if (t == 255) bs[b] = incl;
}

// ---- scan phase 2: add prefix of bucket totals ----
__global__ void scan3_kernel(int* __restrict__ histN, int* __restrict__ histE,
                             const int* __restrict__ bsumN, const int* __restrict__ bsumE) {
    const int arr = blockIdx.x / NBK;
    const int b = blockIdx.x % NBK;
    int* a = arr ? histE : histN;
    const int* bs = arr ? bsumE : bsumN;
    const int t = threadIdx.x;
    int part = 0;
    for (int i = t; i < b; i += 256) part += bs[i];
    __shared__ int red[256];
    red[t] = part;
    __syncthreads();
    for (int off = 128; off > 0; off >>= 1) {
        if (t < off) red[t] += red[t + off];
        __syncthreads();
    }
    a[b * 256 + t] += red[0];
}

// ---- fused: scatter (blocks [0,NBLK)) + gemm blocks [GEMM_A, GEMM_TOTAL) ----
__global__ __launch_bounds__(256) void scatter_gemm_kernel(
        const int* __restrict__ nidx, const int* __restrict__ eidx,
        const int* __restrict__ histN, const int* __restrict__ histE,
        unsigned int* __restrict__ pairsN, unsigned int* __restrict__ pairsE,
        const float* __restrict__ x, const float* __restrict__ w,
        unsigned short* __restrict__ h) {
    __shared__ FusedLds sm;
    const int tid = threadIdx.x;
    if (blockIdx.x < NBLK) {
        const int blk = blockIdx.x;
        for (int j = tid; j < NBK; j += 256) {
            sm.s.a[j] = histN[j * NBLK + blk];
            sm.s.b[j] = histE[j * NBLK + blk];
        }
        __syncthreads();
        const int base = blk * CHUNK;
        for (int i = base + tid; i < base + CHUNK; i += 256) {
            const int n = nidx[i], e = eidx[i];
            const int pn = atomicAdd(&sm.s.a[n >> BSH], 1);
            const int pe = atomicAdd(&sm.s.b[e >> BSH], 1);
            pairsN[pn] = ((unsigned int)e << 8) | (unsigned int)(n & 255);
            pairsE[pe] = ((unsigned int)n << 8) | (unsigned int)(e & 255);
        }
    } else {
        gemm_block(GEMM_A + blockIdx.x - NBLK, x, w, h, sm.wlds, tid);
    }
}

// ---- fine pass: per-bucket local counting sort -> offs + perm (LDS pair cache) ----
__global__ void fine_kernel(const unsigned int* __restrict__ pairsN, const unsigned int* __restrict__ pairsE,
                            const int* __restrict__ histN, const int* __restrict__ histE,
                            int* __restrict__ offsN, int* __restrict__ offsE,
                            int* __restrict__ permN, int* __restrict__ permE) {
    const int arr = blockIdx.x / NBK;
    const int b = blockIdx.x % NBK;
    const unsigned int* pairs = arr ? pairsE : pairsN;
    const int* hist = arr ? histE : histN;
    int* offs = arr ? offsE : offsN;
    int* perm = arr ? permE : permN;
    const int t = threadIdx.x;  // 256
    const int S = hist[b * NBLK];
    const int E = (b + 1 < NBK) ? hist[(b + 1) * NBLK] : NNZC;
    __shared__ int cnt[BUCKW];
    __shared__ int tmp[2][BUCKW];
    __shared__ unsigned int cache[FCAP];
    cnt[t] = 0;
    __syncthreads();
    for (int i = S + t; i < E; i += BUCKW) {
        const unsigned int p = pairs[i];
        const int loc = i - S;
        if (loc < FCAP) cache[loc] = p;
        atomicAdd(&cnt[p & 255u], 1);
    }
    __syncthreads();
    int v = cnt[t];
    int pin = 0;
    tmp[0][t] = v;
    for (int off = 1; off < BUCKW; off <<= 1) {
        __syncthreads();
        int val = tmp[pin][t];
        if (t >= off) val += tmp[pin][t - off];
        tmp[1 - pin][t] = val;
        pin ^= 1;
    }
    __syncthreads();
    const int excl = tmp[pin][t] - v;
    const int id = b * BUCKW + t;
    if (id < 100000) offs[id] = S + excl;
    if (b == NBK - 1 && t == 0) offs[100000] = NNZC;
    __syncthreads();
    cnt[t] = excl;   // reuse as cursors
    __syncthreads();
    for (int i = S + t; i < E; i += BUCKW) {
        const int loc = i - S;
        const unsigned int p = (loc < FCAP) ? cache[loc] : pairs[i];
        const int pos = S + atomicAdd(&cnt[p & 255u], 1);
        perm[pos] = (int)(p >> 8);
    }
}

// ---- gather inner loop: 8 loads in flight, masked tail group ----
__device__ inline void gather_rows(const char* __restrict__ src, const int* __restrict__ perm,
                                   int start, int end, int lane, float& ax, float& ay) {
    const unsigned int laneoff = (unsigned int)lane << 2;
    for (int s0 = start; s0 < end; s0 += 64) {
        const int m = min(end - s0, 64);
        const int myv = perm[s0 + (lane < m ? lane : 0)];
        int t = 0;
        for (; t + 7 < m; t += 8) {
            unsigned int a[8], u[8];
#pragma unroll
            for (int j = 0; j < 8; ++j)
                a[j] = ((unsigned int)__shfl(myv, t + j, 64) << 8) | laneoff;
#pragma unroll
            for (int j = 0; j < 8; ++j) u[j] = *(const unsigned int*)(src + a[j]);
#pragma unroll
            for (int j = 0; j < 8; ++j) {
                ax += __uint_as_float(u[j] << 16);
                ay += __uint_as_float(u[j] & 0xffff0000u);
            }
        }
        if (t < m) {  // masked 8-group tail
            unsigned int a[8], u[8];
            float f[8];
#pragma unroll
            for (int j = 0; j < 8; ++j) {
                const int idx = (t + j < m) ? t + j : t;
                f[j] = (t + j < m) ? 1.f : 0.f;
                a[j] = ((unsigned int)__shfl(myv, idx, 64) << 8) | laneoff;
            }
#pragma unroll
            for (int j = 0; j < 8; ++j) u[j] = *(const unsigned int*)(src + a[j]);
#pragma unroll
            for (int j = 0; j < 8; ++j) {
                ax += f[j] * __uint_as_float(u[j] << 16);
                ay += f[j] * __uint_as_float(u[j] & 0xffff0000u);
            }
        }
    }
}

__global__ void gather_n2e_kernel(const int* __restrict__ perm, const int* __restrict__ offs,
                                  const unsigned short* __restrict__ h,
                                  unsigned short* __restrict__ ef) {
    const int wave = threadIdx.x >> 6;
    const int lane = threadIdx.x & 63;
    const int e = blockIdx.x * 4 + wave;
    const int start = offs[e], end = offs[e + 1];
    float ax = 0.f, ay = 0.f;
    gather_rows((const char*)h, perm, start, end, lane, ax, ay);
    const int deg = end - start;
    const float binv = deg ? 1.f / (float)deg : 0.f;
    const unsigned int o = f2bf2(ax * binv, ay * binv);
    *(unsigned int*)((char*)ef + (((unsigned int)e << 8) | ((unsigned int)lane << 2))) = o;
}

__global__ void gather_e2n_kernel(const int* __restrict__ perm, const int* __restrict__ offs,
                                  const unsigned short* __restrict__ ef,
                                  const float* __restrict__ bias,
                                  float* __restrict__ out) {
    const int wave = threadIdx.x >> 6;
    const int lane = threadIdx.x & 63;
    const int n = blockIdx.x * 4 + wave;
    const int start = offs[n], end = offs[n + 1];
    float ax = 0.f, ay = 0.f;
    gather_rows((const char*)ef, perm, start, end, lane, ax, ay);
    const int deg = end - start;
    const float dinv = deg ? 1.f / (float)deg : 0.f;
    const float2 b = ((const float2*)bias)[lane];
    float2 o;
    o.x = ax * dinv + b.x;
    o.y = ay * dinv + b.y;
    *(float2*)((char*)out + (((unsigned int)n << 9) | ((unsigned int)lane << 3))) = o;
}

extern "C" void kernel_launch(void* const* d_in, const int* in_sizes, int n_in,
                              void* d_out, int out_size, void* d_ws, size_t ws_size,
                              hipStream_t stream) {
    const float* x = (const float*)d_in[0];
    const float* w = (const float*)d_in[1];
    const float* bias = (const float*)d_in[2];
    const int* hei = (const int*)d_in[3];
    const int* nidx = hei;            // row 0: node indices
    const int* eidx = hei + NNZC;     // row 1: edge indices
    float* out = (float*)d_out;

    // ---- carve workspace (256B-aligned chunks), ~79 MB ----
    char* p = (char*)d_ws;
    unsigned short* h = (unsigned short*)p;  p += (size_t)Nn * 128 * 2;      // 25.6 MB
    unsigned short* ef = (unsigned short*)p; p += (size_t)Ne * 128 * 2;      // 25.6 MB
    int* histN = (int*)p;                    p += (size_t)NBK * NBLK * 4 + 256;
    int* histE = (int*)p;                    p += (size_t)NBK * NBLK * 4 + 256;
    int* bsumN = (int*)p;                    p += 1792;
    int* bsumE = (int*)p;                    p += 1792;
    int* offsN = (int*)p;                    p += 400128;                    // 100001 ints
    int* offsE = (int*)p;                    p += 400128;
    int* permN = (int*)p;                    p += (size_t)NNZC * 4;          // 6.4 MB
    int* permE = (int*)p;                    p += (size_t)NNZC * 4;          // 6.4 MB
    unsigned int* pairsN = (unsigned int*)p; p += (size_t)NNZC * 4;          // 6.4 MB
    unsigned int* pairsE = (unsigned int*)p; p += (size_t)NNZC * 4;          // 6.4 MB

    // ---- CSR build with gemm halves fused into both memory-bound stages ----
    hist_gemm_kernel<<<NBLK + GEMM_A, 256, 0, stream>>>(nidx, eidx, histN, histE, x, w, h);
    scan1_kernel<<<2 * NBK, 256, 0, stream>>>(histN, histE, bsumN, bsumE);
    scan3_kernel<<<2 * NBK, 256, 0, stream>>>(histN, histE, bsumN, bsumE);
    scatter_gemm_kernel<<<NBLK + GEMM_B, 256, 0, stream>>>(nidx, eidx, histN, histE,
                                                           pairsN, pairsE, x, w, h);
    fine_kernel<<<2 * NBK, BUCKW, 0, stream>>>(pairsN, pairsE, histN, histE,
                                               offsN, offsE, permN, permE);

    // ---- two gather-side segment sums ----
    gather_n2e_kernel<<<Ne / 4, 256, 0, stream>>>(permE, offsE, h, ef);
    gather_e2n_kernel<<<Nn / 4, 256, 0, stream>>>(permN, offsN, ef, bias, out);
}